// Round 20
// baseline (111.860 us; speedup 1.0000x reference)
//
#include <hip/hip_runtime.h>
#include <stdint.h>
#include <stddef.h>

typedef _Float16 half_t;
typedef __attribute__((ext_vector_type(8))) _Float16 h16x8;
typedef __attribute__((ext_vector_type(4))) _Float16 h16x4;
typedef __attribute__((ext_vector_type(4))) float f32x4;

#define MFMA16(a, b, c) __builtin_amdgcn_mfma_f32_16x16x32_f16(a, b, c, 0, 0, 0)
#define EXP2(x) __builtin_amdgcn_exp2f(x)

// XOR swizzle: 16B-slot permutation within a 128B row. slot in [0,8).
#define SW(row, slot) ((((slot) ^ ((row) & 7))) * 8)

// async global->LDS, 16B per lane; LDS dest = wave-uniform base + lane*16
__device__ __forceinline__ void gload_lds16(const half_t* g, half_t* l) {
    __builtin_amdgcn_global_load_lds(
        (const __attribute__((address_space(1))) void*)g,
        (__attribute__((address_space(3))) void*)l, 16, 0, 0);
}

// ---------------------------------------------------------------------------
// Kernel 0a: convert x fp32 -> fp16
// ---------------------------------------------------------------------------
__global__ __launch_bounds__(256) void cvt_x_kernel(const float* __restrict__ x,
                                                    half_t* __restrict__ xh, int n8) {
    int i = blockIdx.x * blockDim.x + threadIdx.x;
    if (i >= n8) return;
    const float4* xv = (const float4*)x;
    float4 a = xv[i * 2 + 0];
    float4 b = xv[i * 2 + 1];
    h16x8 o;
    o[0] = (half_t)a.x; o[1] = (half_t)a.y; o[2] = (half_t)a.z; o[3] = (half_t)a.w;
    o[4] = (half_t)b.x; o[5] = (half_t)b.y; o[6] = (half_t)b.z; o[7] = (half_t)b.w;
    ((h16x8*)xh)[i] = o;
}

// ---------------------------------------------------------------------------
// Kernel 0b: transpose + convert W [k][n] fp32 -> Wt [p][n][k] fp16
// ---------------------------------------------------------------------------
__global__ __launch_bounds__(256) void cvt_w_kernel(const float* __restrict__ Wq,
                                                    const float* __restrict__ Wk,
                                                    const float* __restrict__ Wv,
                                                    half_t* __restrict__ Wt) {
    __shared__ float t[32][33];
    const float* W = (blockIdx.z == 0) ? Wq : ((blockIdx.z == 1) ? Wk : Wv);
    int k0 = blockIdx.y * 32, n0 = blockIdx.x * 32;
    int tid = threadIdx.x;
    int r = tid >> 3;          // 0..31
    int c4 = (tid & 7) * 4;    // 0..28
    float4 v = *(const float4*)&W[(size_t)(k0 + r) * 1024 + n0 + c4];
    t[r][c4 + 0] = v.x; t[r][c4 + 1] = v.y; t[r][c4 + 2] = v.z; t[r][c4 + 3] = v.w;
    __syncthreads();
    half_t* o = Wt + (size_t)blockIdx.z * 1024 * 1024 + (size_t)(n0 + r) * 1024 + k0 + c4;
    h16x4 h;
    h[0] = (half_t)t[c4 + 0][r];
    h[1] = (half_t)t[c4 + 1][r];
    h[2] = (half_t)t[c4 + 2][r];
    h[3] = (half_t)t[c4 + 3][r];
    *(h16x4*)o = h;
}

// ---------------------------------------------------------------------------
// Kernel 1: QKV projection GEMM, m97 recipe (global_load_lds 16B, linear LDS,
// pre-swizzled source, XOR-swizzled ds_read). BK=64. grid (8, 32, 3).
// ---------------------------------------------------------------------------
__global__ __launch_bounds__(256, 3) void gemm_qkv_kernel(
    const half_t* __restrict__ xh,   // [4096][1024]
    const half_t* __restrict__ Wt,   // [3][1024 n][1024 k]
    const float* __restrict__ bq, const float* __restrict__ bk,
    const float* __restrict__ bv,
    half_t* __restrict__ qkv)
{
    const int p = blockIdx.z;
    const float* bias = (p == 0) ? bq : ((p == 1) ? bk : bv);
    const half_t* Wp = Wt + (size_t)p * 1024 * 1024;
    const int n0 = blockIdx.x * 128, m0 = blockIdx.y * 128;

    __shared__ half_t Al[128][64];   // linear 128B rows; source pre-swizzled
    __shared__ half_t Bl[128][64];

    const int tid = threadIdx.x;
    const int lane = tid & 63, wid = tid >> 6;
    const int wm = wid >> 1, wn = wid & 1;
    const int g = lane >> 4, r = lane & 15;

    const int lrow = lane >> 3;                 // 0..7 within issue
    const int swzc = ((lane & 7) ^ lrow) * 8;   // pre-swizzled source col

    f32x4 acc[4][4];
#pragma unroll
    for (int a = 0; a < 4; a++)
#pragma unroll
        for (int c = 0; c < 4; c++) acc[a][c] = (f32x4){0.f, 0.f, 0.f, 0.f};

    for (int k0 = 0; k0 < 1024; k0 += 64) {
        __syncthreads();
#pragma unroll
        for (int j = 0; j < 4; j++) {
            int issue = wid * 4 + j;
            int row = issue * 8 + lrow;
            gload_lds16(&xh[(size_t)(m0 + row) * 1024 + k0 + swzc], &Al[0][0] + issue * 512);
            gload_lds16(&Wp[(size_t)(n0 + row) * 1024 + k0 + swzc], &Bl[0][0] + issue * 512);
        }
        __syncthreads();

#pragma unroll
        for (int t = 0; t < 2; t++) {
            h16x8 af[4], bf[4];
#pragma unroll
            for (int mi = 0; mi < 4; mi++)
                af[mi] = *(const h16x8*)&Al[wm * 64 + mi * 16 + r][SW(r, t * 4 + g)];
#pragma unroll
            for (int ni = 0; ni < 4; ni++)
                bf[ni] = *(const h16x8*)&Bl[wn * 64 + ni * 16 + r][SW(r, t * 4 + g)];
#pragma unroll
            for (int mi = 0; mi < 4; mi++)
#pragma unroll
                for (int ni = 0; ni < 4; ni++)
                    acc[mi][ni] = MFMA16(af[mi], bf[ni], acc[mi][ni]);
        }
    }

    float bn[4];
#pragma unroll
    for (int ni = 0; ni < 4; ni++) bn[ni] = bias[n0 + wn * 64 + ni * 16 + r];

    if (p == 0) {
        // Q: [bh][s][hd] scattered scalar stores
        half_t* outp = qkv;
#pragma unroll
        for (int mi = 0; mi < 4; mi++) {
#pragma unroll
            for (int ni = 0; ni < 4; ni++) {
                int n = n0 + wn * 64 + ni * 16 + r;
                int hq = n >> 6, hd = n & 63;
#pragma unroll
                for (int i = 0; i < 4; i++) {
                    int m = m0 + wm * 64 + mi * 16 + g * 4 + i;
                    int b = m >> 11, s = m & 2047;
                    outp[(((size_t)(b * 16 + hq) * 2048 + s) << 6) + hd] =
                        (half_t)(acc[mi][ni][i] + bn[ni]);
                }
            }
        }
    } else if (p == 1) {
        // K: fragment-swizzled Kswz[bh][kt][kc=mi][t][g'][r'=g*4+i][j]
        half_t* outp = qkv + (size_t)4194304;
        const int kt = ((m0 & 2047) + wm * 64) >> 6;
        const int bK = (m0 + wm * 64) >> 11;
#pragma unroll
        for (int ni = 0; ni < 4; ni++) {
            int n = n0 + wn * 64 + ni * 16 + r;
            int hK = n >> 6, hd = n & 63;
            int tt = hd >> 5, ggk = (hd >> 3) & 3, jK = hd & 7;
            size_t base = (size_t)(bK * 16 + hK) * 131072 + kt * 4096 + tt * 512 + ggk * 128 + jK;
#pragma unroll
            for (int mi = 0; mi < 4; mi++)
#pragma unroll
                for (int i = 0; i < 4; i++)
                    outp[base + mi * 1024 + (g * 4 + i) * 8] =
                        (half_t)(acc[mi][ni][i] + bn[ni]);
        }
    } else {
        // V: fragment-swizzled Vswz[bh][kt][d=ni][ks][g'][r][j], packed h16x4
        half_t* outp = qkv + (size_t)2 * 4194304;
        const int kt = ((m0 & 2047) + wm * 64) >> 6;
        const int bV = (m0 + wm * 64) >> 11;
        const int jv = (g & 1) * 4, gv_hi = g >> 1;
#pragma unroll
        for (int ni = 0; ni < 4; ni++) {
            int n = n0 + wn * 64 + ni * 16 + r;
            int hV = n >> 6;
            size_t hb = (size_t)(bV * 16 + hV) * 131072 + kt * 4096 + ni * 1024;
#pragma unroll
            for (int mi = 0; mi < 4; mi++) {
                int ks = mi >> 1, ggv = (mi & 1) * 2 + gv_hi;
                h16x4 pk;
#pragma unroll
                for (int i = 0; i < 4; i++) pk[i] = (half_t)(acc[mi][ni][i] + bn[ni]);
                *(h16x4*)&outp[hb + ks * 512 + ggv * 128 + r * 8 + jv] = pk;
            }
        }
    }
}

// ---------------------------------------------------------------------------
// Kernel 2: flash attention, SPLIT-K over the KV range (2 splits x 16 tiles).
// grid 1024 = 2 splits x (16 qblk x 32 bh) -> 4096 waves = 4 waves/SIMD with
// the R13-proven 2-qg loop body (VGPR ~104, compiler keeps the pipeline).
// Split 0 writes normalized partial O (fp32) to d_out; split 1 writes fp16
// partial to o1buf. Both write (m, l) stats. merge_kernel combines.
// ---------------------------------------------------------------------------
__global__ __launch_bounds__(256, 2) void attn_kernel(
    const half_t* __restrict__ Qg,   // [32][2048][64]
    const half_t* __restrict__ Kswz, // [32][32][4][2][4][16][8]
    const half_t* __restrict__ Vswz, // [32][32][4][2][4][16][8]
    half_t* __restrict__ o1buf,      // [65536][64] fp16 partial (split 1)
    float* __restrict__ stats,       // [4][65536]: m0, l0, m1, l1
    float* __restrict__ out)         // [B][S][1024] (split-0 partial, fp32)
{
    __shared__ half_t Pl[4][32][64];    // per-wave P tile (16 KB)

    const int tid = threadIdx.x;
    const int lane = tid & 63, wid = tid >> 6;
    const int g = lane >> 4, r = lane & 15;

    // split + XCD-aware remap (16 q-blocks of a bh land on one XCD)
    const int bid = blockIdx.x;
    const int split = bid >> 9;          // 0 or 1
    const int bid9 = bid & 511;
    const int xcd = bid9 & 7;
    const int t_  = bid9 >> 3;           // 0..63
    const int qblk = t_ & 15;            // 0..15
    const int bh = xcd + 8 * (t_ >> 4);  // 0..31
    const int kt0 = split * 16;

    const int b = bh >> 4, h = bh & 15;
    const half_t* Qb = Qg + (size_t)bh * 131072;
    const half_t* Kp = Kswz + (size_t)bh * 131072;
    const half_t* Vp = Vswz + (size_t)bh * 131072;
    const int q0 = qblk * 128 + wid * 32;
    const int lofs = g * 128 + r * 8;    // per-lane fragment offset (halves)

    // hoisted Q fragments (2 q-groups), pre-scaled by log2(e)
    h16x8 qf[2][2];
#pragma unroll
    for (int qg = 0; qg < 2; qg++)
#pragma unroll
        for (int t = 0; t < 2; t++) {
            qf[qg][t] = *(const h16x8*)&Qb[(size_t)(q0 + qg * 16 + r) * 64 + t * 32 + g * 8];
            qf[qg][t] *= (half_t)1.44269504f;
        }

    const h16x8 ones = {(half_t)1.f, (half_t)1.f, (half_t)1.f, (half_t)1.f,
                        (half_t)1.f, (half_t)1.f, (half_t)1.f, (half_t)1.f};

    f32x4 o[2][4], lsum[2];
#pragma unroll
    for (int qg = 0; qg < 2; qg++) {
#pragma unroll
        for (int d = 0; d < 4; d++) o[qg][d] = (f32x4){0.f, 0.f, 0.f, 0.f};
        lsum[qg] = (f32x4){0.f, 0.f, 0.f, 0.f};
    }
    float m_run[2] = {0.f, 0.f};

    h16x8 kf[8], vf[8];

    auto loadK = [&](int kt) {
#pragma unroll
        for (int kc = 0; kc < 4; kc++)
#pragma unroll
            for (int t = 0; t < 2; t++)
                kf[kc * 2 + t] = *(const h16x8*)&Kp[kt * 4096 + kc * 1024 + t * 512 + lofs];
    };
    auto loadV = [&](int kt) {
#pragma unroll
        for (int d = 0; d < 4; d++)
#pragma unroll
            for (int ks = 0; ks < 2; ks++)
                vf[d * 2 + ks] = *(const h16x8*)&Vp[kt * 4096 + d * 1024 + ks * 512 + lofs];
    };

    auto QKT = [&](f32x4 (&e)[2][4]) {
        __builtin_amdgcn_s_setprio(1);
#pragma unroll
        for (int kc = 0; kc < 4; kc++) {
            e[0][kc] = (f32x4){0.f, 0.f, 0.f, 0.f};
            e[1][kc] = (f32x4){0.f, 0.f, 0.f, 0.f};
#pragma unroll
            for (int t = 0; t < 2; t++) {
                e[0][kc] = MFMA16(kf[kc * 2 + t], qf[0][t], e[0][kc]);
                e[1][kc] = MFMA16(kf[kc * 2 + t], qf[1][t], e[1][kc]);
            }
        }
        __builtin_amdgcn_s_setprio(0);
    };

    auto SOFTMAX_P = [&](f32x4 (&e)[2][4]) {
#pragma unroll
        for (int qg = 0; qg < 2; qg++) {
            float t0 = fmaxf(fmaxf(e[qg][0][0], e[qg][0][1]), e[qg][0][2]);
            float t1 = fmaxf(fmaxf(e[qg][0][3], e[qg][1][0]), e[qg][1][1]);
            float t2 = fmaxf(fmaxf(e[qg][1][2], e[qg][1][3]), e[qg][2][0]);
            float t3 = fmaxf(fmaxf(e[qg][2][1], e[qg][2][2]), e[qg][2][3]);
            float t4 = fmaxf(fmaxf(e[qg][3][0], e[qg][3][1]), e[qg][3][2]);
            float tm = fmaxf(fmaxf(t0, t1), fmaxf(fmaxf(t2, t3), fmaxf(t4, e[qg][3][3])));
            tm = fmaxf(tm, __shfl_xor(tm, 16));
            tm = fmaxf(tm, __shfl_xor(tm, 32));

            // unconditional exp with the CURRENT m_run
#pragma unroll
            for (int kc = 0; kc < 4; kc++)
#pragma unroll
                for (int i = 0; i < 4; i++) e[qg][kc][i] = EXP2(e[qg][kc][i] - m_run[qg]);

            // rare fix-up: a row's max grew by more than 8 (exp2 domain)
            if (!__all(tm <= m_run[qg] + 8.f)) {
                float nm = fmaxf(m_run[qg], tm);
                float sc = EXP2(m_run[qg] - nm);
                m_run[qg] = nm;
#pragma unroll
                for (int kc = 0; kc < 4; kc++)
#pragma unroll
                    for (int i = 0; i < 4; i++) e[qg][kc][i] *= sc;
#pragma unroll
                for (int i = 0; i < 4; i++) {
                    float sci = __shfl(sc, (lane & 48) | (g * 4 + i));
                    lsum[qg][i] *= sci;
#pragma unroll
                    for (int d = 0; d < 4; d++) o[qg][d][i] *= sci;
                }
            }

            // P -> per-wave LDS (swizzled b64 writes)
#pragma unroll
            for (int kc = 0; kc < 4; kc++) {
                h16x4 pk;
#pragma unroll
                for (int i = 0; i < 4; i++) pk[i] = (half_t)e[qg][kc][i];
                *(h16x4*)&Pl[wid][qg * 16 + r][SW(r, 2 * kc + (g >> 1)) + (g & 1) * 4] = pk;
            }
        }
    };

    auto PV = [&]() {
        asm volatile("s_waitcnt lgkmcnt(0)" ::: "memory");
        __builtin_amdgcn_sched_barrier(0);
        __builtin_amdgcn_s_setprio(1);
#pragma unroll
        for (int ks = 0; ks < 2; ks++) {
            h16x8 pf0 = *(const h16x8*)&Pl[wid][r][SW(r, ks * 4 + g)];
            h16x8 pf1 = *(const h16x8*)&Pl[wid][16 + r][SW(r, ks * 4 + g)];
#pragma unroll
            for (int d = 0; d < 4; d++) {
                o[0][d] = MFMA16(pf0, vf[d * 2 + ks], o[0][d]);
                o[1][d] = MFMA16(pf1, vf[d * 2 + ks], o[1][d]);
            }
            // denominator: lsum += P @ ones (full 32-k sum, o-layout)
            lsum[0] = MFMA16(pf0, ones, lsum[0]);
            lsum[1] = MFMA16(pf1, ones, lsum[1]);
        }
        __builtin_amdgcn_s_setprio(0);
    };

    // prologue: e for tile kt0
    f32x4 eA[2][4], eB[2][4];
    loadK(kt0);
    QKT(eA);
    loadK(kt0 + 1);

    for (int kt = kt0; kt < kt0 + 16; kt += 2) {
        // ---- tile kt (state in eA) ----
        loadV(kt);                  // V latency covered by softmax
        SOFTMAX_P(eA);              // ends with P ds_writes
        QKT(eB);                    // tile kt+1 MFMAs drain the ds_write latency
        loadK((kt + 2) & 31);       // wraps (harmless reload)
        PV();                       // lgkmcnt(0) nearly free
        // ---- tile kt+1 (state in eB) ----
        loadV(kt + 1);
        SOFTMAX_P(eB);
        QKT(eA);                    // next pair (garbage on last, unused)
        loadK((kt + 3) & 31);
        PV();
    }

    // ---- epilogue: stats + normalized partial O ----
    const int qbase = bh * 2048 + q0;
    float* m_arr = stats + split * 131072;
    float* l_arr = m_arr + 65536;
#pragma unroll
    for (int qg = 0; qg < 2; qg++) {
        if (r == 0) {
#pragma unroll
            for (int i = 0; i < 4; i++)
                l_arr[qbase + qg * 16 + g * 4 + i] = lsum[qg][i];
        }
        if (g == 0)
            m_arr[qbase + qg * 16 + r] = m_run[qg];
    }

    if (split == 0) {
#pragma unroll
        for (int qg = 0; qg < 2; qg++)
#pragma unroll
            for (int i = 0; i < 4; i++) {
                float inv = 1.0f / lsum[qg][i];
                int s = q0 + qg * 16 + g * 4 + i;
                float* op = out + (size_t)(b * 2048 + s) * 1024 + h * 64 + r;
#pragma unroll
                for (int d = 0; d < 4; d++) op[d * 16] = o[qg][d][i] * inv;
            }
    } else {
#pragma unroll
        for (int qg = 0; qg < 2; qg++)
#pragma unroll
            for (int i = 0; i < 4; i++) {
                float inv = 1.0f / lsum[qg][i];
                half_t* op = o1buf + ((size_t)(qbase + qg * 16 + g * 4 + i) << 6) + r;
#pragma unroll
                for (int d = 0; d < 4; d++) op[d * 16] = (half_t)(o[qg][d][i] * inv);
            }
    }
}

// ---------------------------------------------------------------------------
// Kernel 3: split-K merge.  out = (w0*O0 + w1*O1) / (w0+w1),
// w_i = l_i * 2^(m_i - max(m0,m1)).  grid 4096 x 256 (1 thread = 1 float4).
// ---------------------------------------------------------------------------
__global__ __launch_bounds__(256) void merge_kernel(
    const half_t* __restrict__ o1buf,  // [65536][64] fp16
    const float* __restrict__ stats,   // [4][65536]
    float* __restrict__ out)           // [B][S][1024] (holds O0, updated)
{
    int t = blockIdx.x * 256 + threadIdx.x;   // 0..1048575
    int row = t >> 4;                          // 0..65535 (bh*2048 + s)
    int c4 = (t & 15) * 4;
    float m0 = stats[row], l0 = stats[65536 + row];
    float m1 = stats[131072 + row], l1 = stats[196608 + row];
    float m = fmaxf(m0, m1);
    float w0 = l0 * EXP2(m0 - m);
    float w1 = l1 * EXP2(m1 - m);
    float inv = 1.0f / (w0 + w1);
    int bh = row >> 11, s = row & 2047;
    int b = bh >> 4, h = bh & 15;
    float* op = out + (((size_t)(b * 2048 + s)) << 10) + h * 64 + c4;
    float4 o0 = *(const float4*)op;
    h16x4 ov = *(const h16x4*)&o1buf[((size_t)row << 6) + c4];
    float4 res;
    res.x = (w0 * o0.x + w1 * (float)ov[0]) * inv;
    res.y = (w0 * o0.y + w1 * (float)ov[1]) * inv;
    res.z = (w0 * o0.z + w1 * (float)ov[2]) * inv;
    res.w = (w0 * o0.w + w1 * (float)ov[3]) * inv;
    *(float4*)op = res;
}

// ---------------------------------------------------------------------------
extern "C" void kernel_launch(void* const* d_in, const int* in_sizes, int n_in,
                              void* d_out, int out_size, void* d_ws, size_t ws_size,
                              hipStream_t stream) {
    const float* x  = (const float*)d_in[0];
    const float* Wq = (const float*)d_in[1];
    const float* bq = (const float*)d_in[2];
    const float* Wk = (const float*)d_in[3];
    const float* bk = (const float*)d_in[4];
    const float* Wv = (const float*)d_in[5];
    const float* bv = (const float*)d_in[6];
    float* out = (float*)d_out;

    // ws layout: [0,8MB) xh (gemm input)  -> reused as o1buf by attn split 1
    //            [8,14MB) Wt (gemm input) -> reused as stats (1 MB) by attn
    //            [14,38MB) qkv (Q + Kswz + Vswz)
    half_t* xh    = (half_t*)d_ws;
    half_t* Wt    = (half_t*)((char*)d_ws + (size_t)8 * 1024 * 1024);
    half_t* o1buf = (half_t*)d_ws;                                   // 8 MB
    float*  stats = (float*)((char*)d_ws + (size_t)8 * 1024 * 1024); // 1 MB
    half_t* qkv = (half_t*)((char*)d_ws + (size_t)14 * 1024 * 1024);
    half_t* Qh  = qkv;
    half_t* Kh  = qkv + (size_t)4194304;   // Kswz
    half_t* Vth = qkv + (size_t)8388608;   // Vswz

    cvt_x_kernel<<<2048, 256, 0, stream>>>(x, xh, 524288);
    cvt_w_kernel<<<dim3(32, 32, 3), 256, 0, stream>>>(Wq, Wk, Wv, Wt);
    gemm_qkv_kernel<<<dim3(8, 32, 3), 256, 0, stream>>>(xh, Wt, bq, bk, bv, qkv);
    attn_kernel<<<1024, 256, 0, stream>>>(Qh, Kh, Vth, o1buf, stats, out);
    merge_kernel<<<4096, 256, 0, stream>>>(o1buf, stats, out);
}

// Round 21
// 97.902 us; speedup vs baseline: 1.1426x; 1.1426x over previous
//
#include <hip/hip_runtime.h>
#include <stdint.h>
#include <stddef.h>

typedef _Float16 half_t;
typedef __attribute__((ext_vector_type(8))) _Float16 h16x8;
typedef __attribute__((ext_vector_type(4))) _Float16 h16x4;
typedef __attribute__((ext_vector_type(4))) float f32x4;

#define MFMA16(a, b, c) __builtin_amdgcn_mfma_f32_16x16x32_f16(a, b, c, 0, 0, 0)
#define EXP2(x) __builtin_amdgcn_exp2f(x)

// XOR swizzle: 16B-slot permutation within a 128B row. slot in [0,8).
#define SW(row, slot) ((((slot) ^ ((row) & 7))) * 8)

// async global->LDS, 16B per lane; LDS dest = wave-uniform base + lane*16
__device__ __forceinline__ void gload_lds16(const half_t* g, half_t* l) {
    __builtin_amdgcn_global_load_lds(
        (const __attribute__((address_space(1))) void*)g,
        (__attribute__((address_space(3))) void*)l, 16, 0, 0);
}

// ---------------------------------------------------------------------------
// Kernel 0a: convert x fp32 -> fp16
// ---------------------------------------------------------------------------
__global__ __launch_bounds__(256) void cvt_x_kernel(const float* __restrict__ x,
                                                    half_t* __restrict__ xh, int n8) {
    int i = blockIdx.x * blockDim.x + threadIdx.x;
    if (i >= n8) return;
    const float4* xv = (const float4*)x;
    float4 a = xv[i * 2 + 0];
    float4 b = xv[i * 2 + 1];
    h16x8 o;
    o[0] = (half_t)a.x; o[1] = (half_t)a.y; o[2] = (half_t)a.z; o[3] = (half_t)a.w;
    o[4] = (half_t)b.x; o[5] = (half_t)b.y; o[6] = (half_t)b.z; o[7] = (half_t)b.w;
    ((h16x8*)xh)[i] = o;
}

// ---------------------------------------------------------------------------
// Kernel 0b: transpose + convert W [k][n] fp32 -> Wt [p][n][k] fp16
// ---------------------------------------------------------------------------
__global__ __launch_bounds__(256) void cvt_w_kernel(const float* __restrict__ Wq,
                                                    const float* __restrict__ Wk,
                                                    const float* __restrict__ Wv,
                                                    half_t* __restrict__ Wt) {
    __shared__ float t[32][33];
    const float* W = (blockIdx.z == 0) ? Wq : ((blockIdx.z == 1) ? Wk : Wv);
    int k0 = blockIdx.y * 32, n0 = blockIdx.x * 32;
    int tid = threadIdx.x;
    int r = tid >> 3;          // 0..31
    int c4 = (tid & 7) * 4;    // 0..28
    float4 v = *(const float4*)&W[(size_t)(k0 + r) * 1024 + n0 + c4];
    t[r][c4 + 0] = v.x; t[r][c4 + 1] = v.y; t[r][c4 + 2] = v.z; t[r][c4 + 3] = v.w;
    __syncthreads();
    half_t* o = Wt + (size_t)blockIdx.z * 1024 * 1024 + (size_t)(n0 + r) * 1024 + k0 + c4;
    h16x4 h;
    h[0] = (half_t)t[c4 + 0][r];
    h[1] = (half_t)t[c4 + 1][r];
    h[2] = (half_t)t[c4 + 2][r];
    h[3] = (half_t)t[c4 + 3][r];
    *(h16x4*)o = h;
}

// ---------------------------------------------------------------------------
// Kernel 1: QKV projection GEMM, m97 recipe (global_load_lds 16B, linear LDS,
// pre-swizzled source, XOR-swizzled ds_read). BK=64. grid (8, 32, 3).
// ---------------------------------------------------------------------------
__global__ __launch_bounds__(256, 3) void gemm_qkv_kernel(
    const half_t* __restrict__ xh,   // [4096][1024]
    const half_t* __restrict__ Wt,   // [3][1024 n][1024 k]
    const float* __restrict__ bq, const float* __restrict__ bk,
    const float* __restrict__ bv,
    half_t* __restrict__ qkv)
{
    const int p = blockIdx.z;
    const float* bias = (p == 0) ? bq : ((p == 1) ? bk : bv);
    const half_t* Wp = Wt + (size_t)p * 1024 * 1024;
    const int n0 = blockIdx.x * 128, m0 = blockIdx.y * 128;

    __shared__ half_t Al[128][64];   // linear 128B rows; source pre-swizzled
    __shared__ half_t Bl[128][64];

    const int tid = threadIdx.x;
    const int lane = tid & 63, wid = tid >> 6;
    const int wm = wid >> 1, wn = wid & 1;
    const int g = lane >> 4, r = lane & 15;

    const int lrow = lane >> 3;                 // 0..7 within issue
    const int swzc = ((lane & 7) ^ lrow) * 8;   // pre-swizzled source col

    f32x4 acc[4][4];
#pragma unroll
    for (int a = 0; a < 4; a++)
#pragma unroll
        for (int c = 0; c < 4; c++) acc[a][c] = (f32x4){0.f, 0.f, 0.f, 0.f};

    for (int k0 = 0; k0 < 1024; k0 += 64) {
        __syncthreads();
#pragma unroll
        for (int j = 0; j < 4; j++) {
            int issue = wid * 4 + j;
            int row = issue * 8 + lrow;
            gload_lds16(&xh[(size_t)(m0 + row) * 1024 + k0 + swzc], &Al[0][0] + issue * 512);
            gload_lds16(&Wp[(size_t)(n0 + row) * 1024 + k0 + swzc], &Bl[0][0] + issue * 512);
        }
        __syncthreads();

#pragma unroll
        for (int t = 0; t < 2; t++) {
            h16x8 af[4], bf[4];
#pragma unroll
            for (int mi = 0; mi < 4; mi++)
                af[mi] = *(const h16x8*)&Al[wm * 64 + mi * 16 + r][SW(r, t * 4 + g)];
#pragma unroll
            for (int ni = 0; ni < 4; ni++)
                bf[ni] = *(const h16x8*)&Bl[wn * 64 + ni * 16 + r][SW(r, t * 4 + g)];
#pragma unroll
            for (int mi = 0; mi < 4; mi++)
#pragma unroll
                for (int ni = 0; ni < 4; ni++)
                    acc[mi][ni] = MFMA16(af[mi], bf[ni], acc[mi][ni]);
        }
    }

    float bn[4];
#pragma unroll
    for (int ni = 0; ni < 4; ni++) bn[ni] = bias[n0 + wn * 64 + ni * 16 + r];

    if (p == 0) {
        // Q: [bh][s][hd] scattered scalar stores
        half_t* outp = qkv;
#pragma unroll
        for (int mi = 0; mi < 4; mi++) {
#pragma unroll
            for (int ni = 0; ni < 4; ni++) {
                int n = n0 + wn * 64 + ni * 16 + r;
                int hq = n >> 6, hd = n & 63;
#pragma unroll
                for (int i = 0; i < 4; i++) {
                    int m = m0 + wm * 64 + mi * 16 + g * 4 + i;
                    int b = m >> 11, s = m & 2047;
                    outp[(((size_t)(b * 16 + hq) * 2048 + s) << 6) + hd] =
                        (half_t)(acc[mi][ni][i] + bn[ni]);
                }
            }
        }
    } else if (p == 1) {
        // K: fragment-swizzled Kswz[bh][kt][kc=mi][t][g'][r'=g*4+i][j]
        half_t* outp = qkv + (size_t)4194304;
        const int kt = ((m0 & 2047) + wm * 64) >> 6;
        const int bK = (m0 + wm * 64) >> 11;
#pragma unroll
        for (int ni = 0; ni < 4; ni++) {
            int n = n0 + wn * 64 + ni * 16 + r;
            int hK = n >> 6, hd = n & 63;
            int tt = hd >> 5, ggk = (hd >> 3) & 3, jK = hd & 7;
            size_t base = (size_t)(bK * 16 + hK) * 131072 + kt * 4096 + tt * 512 + ggk * 128 + jK;
#pragma unroll
            for (int mi = 0; mi < 4; mi++)
#pragma unroll
                for (int i = 0; i < 4; i++)
                    outp[base + mi * 1024 + (g * 4 + i) * 8] =
                        (half_t)(acc[mi][ni][i] + bn[ni]);
        }
    } else {
        // V: fragment-swizzled Vswz[bh][kt][d=ni][ks][g'][r][j], packed h16x4
        half_t* outp = qkv + (size_t)2 * 4194304;
        const int kt = ((m0 & 2047) + wm * 64) >> 6;
        const int bV = (m0 + wm * 64) >> 11;
        const int jv = (g & 1) * 4, gv_hi = g >> 1;
#pragma unroll
        for (int ni = 0; ni < 4; ni++) {
            int n = n0 + wn * 64 + ni * 16 + r;
            int hV = n >> 6;
            size_t hb = (size_t)(bV * 16 + hV) * 131072 + kt * 4096 + ni * 1024;
#pragma unroll
            for (int mi = 0; mi < 4; mi++) {
                int ks = mi >> 1, ggv = (mi & 1) * 2 + gv_hi;
                h16x4 pk;
#pragma unroll
                for (int i = 0; i < 4; i++) pk[i] = (half_t)(acc[mi][ni][i] + bn[ni]);
                *(h16x4*)&outp[hb + ks * 512 + ggv * 128 + r * 8 + jv] = pk;
            }
        }
    }
}

// ---------------------------------------------------------------------------
// Kernel 2: flash attention. Barrier-free, coalesced direct-global K/V,
// 2-tile pipeline (single V buffer). Body order puts QKT[t+1] between
// P-write[t] and PV[t] so the lgkmcnt(0) is pre-drained. MFMA lsum
// denominator; s_setprio around MFMA clusters.  [best measured: 54.0 us]
// ---------------------------------------------------------------------------
__global__ __launch_bounds__(256, 2) void attn_kernel(
    const half_t* __restrict__ Qg,   // [32][2048][64]
    const half_t* __restrict__ Kswz, // [32][32][4][2][4][16][8]
    const half_t* __restrict__ Vswz, // [32][32][4][2][4][16][8]
    float* __restrict__ out)         // [B][S][1024]
{
    __shared__ half_t Pl[4][32][64];    // per-wave P tile (16 KB)

    const int tid = threadIdx.x;
    const int lane = tid & 63, wid = tid >> 6;
    const int g = lane >> 4, r = lane & 15;

    // XCD-aware remap: all 16 q-blocks of a bh land on one XCD (4 bh/XCD).
    const int bid = blockIdx.x;
    const int xcd = bid & 7;
    const int t_  = bid >> 3;            // 0..63
    const int qblk = t_ & 15;            // 0..15
    const int bh = xcd + 8 * (t_ >> 4);  // 0..31

    const int b = bh >> 4, h = bh & 15;
    const half_t* Qb = Qg + (size_t)bh * 131072;
    const half_t* Kp = Kswz + (size_t)bh * 131072;
    const half_t* Vp = Vswz + (size_t)bh * 131072;
    const int q0 = qblk * 128 + wid * 32;
    const int lofs = g * 128 + r * 8;    // per-lane fragment offset (halves)

    // hoisted Q fragments (2 q-groups), pre-scaled by log2(e)
    h16x8 qf[2][2];
#pragma unroll
    for (int qg = 0; qg < 2; qg++)
#pragma unroll
        for (int t = 0; t < 2; t++) {
            qf[qg][t] = *(const h16x8*)&Qb[(size_t)(q0 + qg * 16 + r) * 64 + t * 32 + g * 8];
            qf[qg][t] *= (half_t)1.44269504f;
        }

    const h16x8 ones = {(half_t)1.f, (half_t)1.f, (half_t)1.f, (half_t)1.f,
                        (half_t)1.f, (half_t)1.f, (half_t)1.f, (half_t)1.f};

    f32x4 o[2][4], lsum[2];
#pragma unroll
    for (int qg = 0; qg < 2; qg++) {
#pragma unroll
        for (int d = 0; d < 4; d++) o[qg][d] = (f32x4){0.f, 0.f, 0.f, 0.f};
        lsum[qg] = (f32x4){0.f, 0.f, 0.f, 0.f};
    }
    float m_run[2] = {0.f, 0.f};

    h16x8 kf[8], vf[8];

    auto loadK = [&](int kt) {
#pragma unroll
        for (int kc = 0; kc < 4; kc++)
#pragma unroll
            for (int t = 0; t < 2; t++)
                kf[kc * 2 + t] = *(const h16x8*)&Kp[kt * 4096 + kc * 1024 + t * 512 + lofs];
    };
    auto loadV = [&](int kt) {
#pragma unroll
        for (int d = 0; d < 4; d++)
#pragma unroll
            for (int ks = 0; ks < 2; ks++)
                vf[d * 2 + ks] = *(const h16x8*)&Vp[kt * 4096 + d * 1024 + ks * 512 + lofs];
    };

    auto QKT = [&](f32x4 (&e)[2][4]) {
        __builtin_amdgcn_s_setprio(1);
#pragma unroll
        for (int kc = 0; kc < 4; kc++) {
            e[0][kc] = (f32x4){0.f, 0.f, 0.f, 0.f};
            e[1][kc] = (f32x4){0.f, 0.f, 0.f, 0.f};
#pragma unroll
            for (int t = 0; t < 2; t++) {
                e[0][kc] = MFMA16(kf[kc * 2 + t], qf[0][t], e[0][kc]);
                e[1][kc] = MFMA16(kf[kc * 2 + t], qf[1][t], e[1][kc]);
            }
        }
        __builtin_amdgcn_s_setprio(0);
    };

    auto SOFTMAX_P = [&](f32x4 (&e)[2][4]) {
#pragma unroll
        for (int qg = 0; qg < 2; qg++) {
            float t0 = fmaxf(fmaxf(e[qg][0][0], e[qg][0][1]), e[qg][0][2]);
            float t1 = fmaxf(fmaxf(e[qg][0][3], e[qg][1][0]), e[qg][1][1]);
            float t2 = fmaxf(fmaxf(e[qg][1][2], e[qg][1][3]), e[qg][2][0]);
            float t3 = fmaxf(fmaxf(e[qg][2][1], e[qg][2][2]), e[qg][2][3]);
            float t4 = fmaxf(fmaxf(e[qg][3][0], e[qg][3][1]), e[qg][3][2]);
            float tm = fmaxf(fmaxf(t0, t1), fmaxf(fmaxf(t2, t3), fmaxf(t4, e[qg][3][3])));
            tm = fmaxf(tm, __shfl_xor(tm, 16));
            tm = fmaxf(tm, __shfl_xor(tm, 32));

            // unconditional exp with the CURRENT m_run
#pragma unroll
            for (int kc = 0; kc < 4; kc++)
#pragma unroll
                for (int i = 0; i < 4; i++) e[qg][kc][i] = EXP2(e[qg][kc][i] - m_run[qg]);

            // rare fix-up: a row's max grew by more than 8 (exp2 domain)
            if (!__all(tm <= m_run[qg] + 8.f)) {
                float nm = fmaxf(m_run[qg], tm);
                float sc = EXP2(m_run[qg] - nm);
                m_run[qg] = nm;
#pragma unroll
                for (int kc = 0; kc < 4; kc++)
#pragma unroll
                    for (int i = 0; i < 4; i++) e[qg][kc][i] *= sc;
#pragma unroll
                for (int i = 0; i < 4; i++) {
                    float sci = __shfl(sc, (lane & 48) | (g * 4 + i));
                    lsum[qg][i] *= sci;
#pragma unroll
                    for (int d = 0; d < 4; d++) o[qg][d][i] *= sci;
                }
            }

            // P -> per-wave LDS (swizzled b64 writes)
#pragma unroll
            for (int kc = 0; kc < 4; kc++) {
                h16x4 pk;
#pragma unroll
                for (int i = 0; i < 4; i++) pk[i] = (half_t)e[qg][kc][i];
                *(h16x4*)&Pl[wid][qg * 16 + r][SW(r, 2 * kc + (g >> 1)) + (g & 1) * 4] = pk;
            }
        }
    };

    auto PV = [&]() {
        asm volatile("s_waitcnt lgkmcnt(0)" ::: "memory");
        __builtin_amdgcn_sched_barrier(0);
        __builtin_amdgcn_s_setprio(1);
#pragma unroll
        for (int ks = 0; ks < 2; ks++) {
            h16x8 pf0 = *(const h16x8*)&Pl[wid][r][SW(r, ks * 4 + g)];
            h16x8 pf1 = *(const h16x8*)&Pl[wid][16 + r][SW(r, ks * 4 + g)];
#pragma unroll
            for (int d = 0; d < 4; d++) {
                o[0][d] = MFMA16(pf0, vf[d * 2 + ks], o[0][d]);
                o[1][d] = MFMA16(pf1, vf[d * 2 + ks], o[1][d]);
            }
            // denominator: lsum += P @ ones (full 32-k sum, o-layout)
            lsum[0] = MFMA16(pf0, ones, lsum[0]);
            lsum[1] = MFMA16(pf1, ones, lsum[1]);
        }
        __builtin_amdgcn_s_setprio(0);
    };

    // prologue: e for tile 0
    f32x4 eA[2][4], eB[2][4];
    loadK(0);
    QKT(eA);
    loadK(1);

    for (int kt = 0; kt < 32; kt += 2) {
        // ---- tile kt (state in eA) ----
        loadV(kt);                  // V latency covered by softmax
        SOFTMAX_P(eA);              // ends with P ds_writes
        QKT(eB);                    // tile kt+1 MFMAs drain the ds_write latency
        loadK((kt + 2) & 31);       // kf free after QKT; wraps (harmless)
        PV();                       // lgkmcnt(0) nearly free
        // ---- tile kt+1 (state in eB) ----
        loadV(kt + 1);
        SOFTMAX_P(eB);
        QKT(eA);                    // tile kt+2 (garbage on last pair, unused)
        loadK((kt + 3) & 31);
        PV();
    }

    // epilogue: lsum already holds per-row denominators in o-layout
#pragma unroll
    for (int qg = 0; qg < 2; qg++)
#pragma unroll
        for (int i = 0; i < 4; i++) {
            float inv = 1.0f / lsum[qg][i];
            int s = q0 + qg * 16 + g * 4 + i;
            float* op = out + (size_t)(b * 2048 + s) * 1024 + h * 64 + r;
#pragma unroll
            for (int d = 0; d < 4; d++) op[d * 16] = o[qg][d][i] * inv;
        }
}

// ---------------------------------------------------------------------------
extern "C" void kernel_launch(void* const* d_in, const int* in_sizes, int n_in,
                              void* d_out, int out_size, void* d_ws, size_t ws_size,
                              hipStream_t stream) {
    const float* x  = (const float*)d_in[0];
    const float* Wq = (const float*)d_in[1];
    const float* bq = (const float*)d_in[2];
    const float* Wk = (const float*)d_in[3];
    const float* bk = (const float*)d_in[4];
    const float* Wv = (const float*)d_in[5];
    const float* bv = (const float*)d_in[6];
    float* out = (float*)d_out;

    half_t* xh  = (half_t*)d_ws;
    half_t* Wt  = (half_t*)((char*)d_ws + (size_t)8 * 1024 * 1024);
    half_t* qkv = (half_t*)((char*)d_ws + (size_t)14 * 1024 * 1024);
    half_t* Qh  = qkv;
    half_t* Kh  = qkv + (size_t)4194304;   // Kswz
    half_t* Vth = qkv + (size_t)8388608;   // Vswz

    cvt_x_kernel<<<2048, 256, 0, stream>>>(x, xh, 524288);
    cvt_w_kernel<<<dim3(32, 32, 3), 256, 0, stream>>>(Wq, Wk, Wv, Wt);
    gemm_qkv_kernel<<<dim3(8, 32, 3), 256, 0, stream>>>(xh, Wt, bq, bk, bv, qkv);
    attn_kernel<<<dim3(512), 256, 0, stream>>>(Qh, Kh, Vth, out);
}

// Round 22
// 95.192 us; speedup vs baseline: 1.1751x; 1.0285x over previous
//
#include <hip/hip_runtime.h>
#include <stdint.h>
#include <stddef.h>

typedef _Float16 half_t;
typedef __attribute__((ext_vector_type(8))) _Float16 h16x8;
typedef __attribute__((ext_vector_type(4))) _Float16 h16x4;
typedef __attribute__((ext_vector_type(4))) float f32x4;

#define MFMA16(a, b, c) __builtin_amdgcn_mfma_f32_16x16x32_f16(a, b, c, 0, 0, 0)
#define EXP2(x) __builtin_amdgcn_exp2f(x)

// XOR swizzle: 16B-slot permutation within a 128B row. slot in [0,8).
#define SW(row, slot) ((((slot) ^ ((row) & 7))) * 8)

// async global->LDS, 16B per lane; LDS dest = wave-uniform base + lane*16
__device__ __forceinline__ void gload_lds16(const half_t* g, half_t* l) {
    __builtin_amdgcn_global_load_lds(
        (const __attribute__((address_space(1))) void*)g,
        (__attribute__((address_space(3))) void*)l, 16, 0, 0);
}

// ---------------------------------------------------------------------------
// Kernel 0: fused converts. blocks [0,2048): x fp32->fp16 (1 h16x8/thread).
// blocks [2048,5120): W [k][n] fp32 -> Wt[p][n][k] fp16, 32x32 LDS tiles.
// ---------------------------------------------------------------------------
__global__ __launch_bounds__(256) void cvt_kernel(
    const float* __restrict__ x,
    const float* __restrict__ Wq, const float* __restrict__ Wk,
    const float* __restrict__ Wv,
    half_t* __restrict__ xh, half_t* __restrict__ Wt) {
    __shared__ float t[32][33];
    const int bid = blockIdx.x;
    const int tid = threadIdx.x;
    if (bid < 2048) {
        int i = bid * 256 + tid;        // < 524288
        const float4* xv = (const float4*)x;
        float4 a = xv[i * 2 + 0];
        float4 b = xv[i * 2 + 1];
        h16x8 o;
        o[0] = (half_t)a.x; o[1] = (half_t)a.y; o[2] = (half_t)a.z; o[3] = (half_t)a.w;
        o[4] = (half_t)b.x; o[5] = (half_t)b.y; o[6] = (half_t)b.z; o[7] = (half_t)b.w;
        ((h16x8*)xh)[i] = o;
        return;
    }
    const int widx = bid - 2048;        // 0..3071
    const int p = widx >> 10;
    const int tile = widx & 1023;
    const int k0 = (tile >> 5) * 32, n0 = (tile & 31) * 32;
    const float* W = (p == 0) ? Wq : ((p == 1) ? Wk : Wv);
    int r = tid >> 3;          // 0..31
    int c4 = (tid & 7) * 4;    // 0..28
    float4 v = *(const float4*)&W[(size_t)(k0 + r) * 1024 + n0 + c4];
    t[r][c4 + 0] = v.x; t[r][c4 + 1] = v.y; t[r][c4 + 2] = v.z; t[r][c4 + 3] = v.w;
    __syncthreads();
    half_t* o = Wt + (size_t)p * 1024 * 1024 + (size_t)(n0 + r) * 1024 + k0 + c4;
    h16x4 h;
    h[0] = (half_t)t[c4 + 0][r];
    h[1] = (half_t)t[c4 + 1][r];
    h[2] = (half_t)t[c4 + 2][r];
    h[3] = (half_t)t[c4 + 3][r];
    *(h16x4*)o = h;
}

// ---------------------------------------------------------------------------
// Kernel 1: QKV projection GEMM, m97 recipe (global_load_lds 16B, linear LDS,
// pre-swizzled source, XOR-swizzled ds_read). BK=64. grid (8, 32, 3).
// ---------------------------------------------------------------------------
__global__ __launch_bounds__(256, 3) void gemm_qkv_kernel(
    const half_t* __restrict__ xh,   // [4096][1024]
    const half_t* __restrict__ Wt,   // [3][1024 n][1024 k]
    const float* __restrict__ bq, const float* __restrict__ bk,
    const float* __restrict__ bv,
    half_t* __restrict__ qkv)
{
    const int p = blockIdx.z;
    const float* bias = (p == 0) ? bq : ((p == 1) ? bk : bv);
    const half_t* Wp = Wt + (size_t)p * 1024 * 1024;
    const int n0 = blockIdx.x * 128, m0 = blockIdx.y * 128;

    __shared__ half_t Al[128][64];   // linear 128B rows; source pre-swizzled
    __shared__ half_t Bl[128][64];

    const int tid = threadIdx.x;
    const int lane = tid & 63, wid = tid >> 6;
    const int wm = wid >> 1, wn = wid & 1;
    const int g = lane >> 4, r = lane & 15;

    const int lrow = lane >> 3;                 // 0..7 within issue
    const int swzc = ((lane & 7) ^ lrow) * 8;   // pre-swizzled source col

    f32x4 acc[4][4];
#pragma unroll
    for (int a = 0; a < 4; a++)
#pragma unroll
        for (int c = 0; c < 4; c++) acc[a][c] = (f32x4){0.f, 0.f, 0.f, 0.f};

    for (int k0 = 0; k0 < 1024; k0 += 64) {
        __syncthreads();
#pragma unroll
        for (int j = 0; j < 4; j++) {
            int issue = wid * 4 + j;
            int row = issue * 8 + lrow;
            gload_lds16(&xh[(size_t)(m0 + row) * 1024 + k0 + swzc], &Al[0][0] + issue * 512);
            gload_lds16(&Wp[(size_t)(n0 + row) * 1024 + k0 + swzc], &Bl[0][0] + issue * 512);
        }
        __syncthreads();

#pragma unroll
        for (int t = 0; t < 2; t++) {
            h16x8 af[4], bf[4];
#pragma unroll
            for (int mi = 0; mi < 4; mi++)
                af[mi] = *(const h16x8*)&Al[wm * 64 + mi * 16 + r][SW(r, t * 4 + g)];
#pragma unroll
            for (int ni = 0; ni < 4; ni++)
                bf[ni] = *(const h16x8*)&Bl[wn * 64 + ni * 16 + r][SW(r, t * 4 + g)];
#pragma unroll
            for (int mi = 0; mi < 4; mi++)
#pragma unroll
                for (int ni = 0; ni < 4; ni++)
                    acc[mi][ni] = MFMA16(af[mi], bf[ni], acc[mi][ni]);
        }
    }

    float bn[4];
#pragma unroll
    for (int ni = 0; ni < 4; ni++) bn[ni] = bias[n0 + wn * 64 + ni * 16 + r];

    if (p == 0) {
        // Q: [bh][s][hd] scattered scalar stores
        half_t* outp = qkv;
#pragma unroll
        for (int mi = 0; mi < 4; mi++) {
#pragma unroll
            for (int ni = 0; ni < 4; ni++) {
                int n = n0 + wn * 64 + ni * 16 + r;
                int hq = n >> 6, hd = n & 63;
#pragma unroll
                for (int i = 0; i < 4; i++) {
                    int m = m0 + wm * 64 + mi * 16 + g * 4 + i;
                    int b = m >> 11, s = m & 2047;
                    outp[(((size_t)(b * 16 + hq) * 2048 + s) << 6) + hd] =
                        (half_t)(acc[mi][ni][i] + bn[ni]);
                }
            }
        }
    } else if (p == 1) {
        // K: fragment-swizzled Kswz[bh][kt][kc=mi][t][g'][r'=g*4+i][j]
        half_t* outp = qkv + (size_t)4194304;
        const int kt = ((m0 & 2047) + wm * 64) >> 6;
        const int bK = (m0 + wm * 64) >> 11;
#pragma unroll
        for (int ni = 0; ni < 4; ni++) {
            int n = n0 + wn * 64 + ni * 16 + r;
            int hK = n >> 6, hd = n & 63;
            int tt = hd >> 5, ggk = (hd >> 3) & 3, jK = hd & 7;
            size_t base = (size_t)(bK * 16 + hK) * 131072 + kt * 4096 + tt * 512 + ggk * 128 + jK;
#pragma unroll
            for (int mi = 0; mi < 4; mi++)
#pragma unroll
                for (int i = 0; i < 4; i++)
                    outp[base + mi * 1024 + (g * 4 + i) * 8] =
                        (half_t)(acc[mi][ni][i] + bn[ni]);
        }
    } else {
        // V: fragment-swizzled Vswz[bh][kt][d=ni][ks][g'][r][j], packed h16x4
        half_t* outp = qkv + (size_t)2 * 4194304;
        const int kt = ((m0 & 2047) + wm * 64) >> 6;
        const int bV = (m0 + wm * 64) >> 11;
        const int jv = (g & 1) * 4, gv_hi = g >> 1;
#pragma unroll
        for (int ni = 0; ni < 4; ni++) {
            int n = n0 + wn * 64 + ni * 16 + r;
            int hV = n >> 6;
            size_t hb = (size_t)(bV * 16 + hV) * 131072 + kt * 4096 + ni * 1024;
#pragma unroll
            for (int mi = 0; mi < 4; mi++) {
                int ks = mi >> 1, ggv = (mi & 1) * 2 + gv_hi;
                h16x4 pk;
#pragma unroll
                for (int i = 0; i < 4; i++) pk[i] = (half_t)(acc[mi][ni][i] + bn[ni]);
                *(h16x4*)&outp[hb + ks * 512 + ggv * 128 + r * 8 + jv] = pk;
            }
        }
    }
}

// ---------------------------------------------------------------------------
// Kernel 2: flash attention. Barrier-free, coalesced direct-global K/V,
// 2-tile pipeline (single V buffer). Body order puts QKT[t+1] between
// P-write[t] and PV[t] so the lgkmcnt(0) is pre-drained. MFMA lsum
// denominator; s_setprio around MFMA clusters.  [best measured: 54.0 us]
// ---------------------------------------------------------------------------
__global__ __launch_bounds__(256, 2) void attn_kernel(
    const half_t* __restrict__ Qg,   // [32][2048][64]
    const half_t* __restrict__ Kswz, // [32][32][4][2][4][16][8]
    const half_t* __restrict__ Vswz, // [32][32][4][2][4][16][8]
    float* __restrict__ out)         // [B][S][1024]
{
    __shared__ half_t Pl[4][32][64];    // per-wave P tile (16 KB)

    const int tid = threadIdx.x;
    const int lane = tid & 63, wid = tid >> 6;
    const int g = lane >> 4, r = lane & 15;

    // XCD-aware remap: all 16 q-blocks of a bh land on one XCD (4 bh/XCD).
    const int bid = blockIdx.x;
    const int xcd = bid & 7;
    const int t_  = bid >> 3;            // 0..63
    const int qblk = t_ & 15;            // 0..15
    const int bh = xcd + 8 * (t_ >> 4);  // 0..31

    const int b = bh >> 4, h = bh & 15;
    const half_t* Qb = Qg + (size_t)bh * 131072;
    const half_t* Kp = Kswz + (size_t)bh * 131072;
    const half_t* Vp = Vswz + (size_t)bh * 131072;
    const int q0 = qblk * 128 + wid * 32;
    const int lofs = g * 128 + r * 8;    // per-lane fragment offset (halves)

    // hoisted Q fragments (2 q-groups), pre-scaled by log2(e)
    h16x8 qf[2][2];
#pragma unroll
    for (int qg = 0; qg < 2; qg++)
#pragma unroll
        for (int t = 0; t < 2; t++) {
            qf[qg][t] = *(const h16x8*)&Qb[(size_t)(q0 + qg * 16 + r) * 64 + t * 32 + g * 8];
            qf[qg][t] *= (half_t)1.44269504f;
        }

    const h16x8 ones = {(half_t)1.f, (half_t)1.f, (half_t)1.f, (half_t)1.f,
                        (half_t)1.f, (half_t)1.f, (half_t)1.f, (half_t)1.f};

    f32x4 o[2][4], lsum[2];
#pragma unroll
    for (int qg = 0; qg < 2; qg++) {
#pragma unroll
        for (int d = 0; d < 4; d++) o[qg][d] = (f32x4){0.f, 0.f, 0.f, 0.f};
        lsum[qg] = (f32x4){0.f, 0.f, 0.f, 0.f};
    }
    float m_run[2] = {0.f, 0.f};

    h16x8 kf[8], vf[8];

    auto loadK = [&](int kt) {
#pragma unroll
        for (int kc = 0; kc < 4; kc++)
#pragma unroll
            for (int t = 0; t < 2; t++)
                kf[kc * 2 + t] = *(const h16x8*)&Kp[kt * 4096 + kc * 1024 + t * 512 + lofs];
    };
    auto loadV = [&](int kt) {
#pragma unroll
        for (int d = 0; d < 4; d++)
#pragma unroll
            for (int ks = 0; ks < 2; ks++)
                vf[d * 2 + ks] = *(const h16x8*)&Vp[kt * 4096 + d * 1024 + ks * 512 + lofs];
    };

    auto QKT = [&](f32x4 (&e)[2][4]) {
        __builtin_amdgcn_s_setprio(1);
#pragma unroll
        for (int kc = 0; kc < 4; kc++) {
            e[0][kc] = (f32x4){0.f, 0.f, 0.f, 0.f};
            e[1][kc] = (f32x4){0.f, 0.f, 0.f, 0.f};
#pragma unroll
            for (int t = 0; t < 2; t++) {
                e[0][kc] = MFMA16(kf[kc * 2 + t], qf[0][t], e[0][kc]);
                e[1][kc] = MFMA16(kf[kc * 2 + t], qf[1][t], e[1][kc]);
            }
        }
        __builtin_amdgcn_s_setprio(0);
    };

    auto SOFTMAX_P = [&](f32x4 (&e)[2][4]) {
#pragma unroll
        for (int qg = 0; qg < 2; qg++) {
            float t0 = fmaxf(fmaxf(e[qg][0][0], e[qg][0][1]), e[qg][0][2]);
            float t1 = fmaxf(fmaxf(e[qg][0][3], e[qg][1][0]), e[qg][1][1]);
            float t2 = fmaxf(fmaxf(e[qg][1][2], e[qg][1][3]), e[qg][2][0]);
            float t3 = fmaxf(fmaxf(e[qg][2][1], e[qg][2][2]), e[qg][2][3]);
            float t4 = fmaxf(fmaxf(e[qg][3][0], e[qg][3][1]), e[qg][3][2]);
            float tm = fmaxf(fmaxf(t0, t1), fmaxf(fmaxf(t2, t3), fmaxf(t4, e[qg][3][3])));
            tm = fmaxf(tm, __shfl_xor(tm, 16));
            tm = fmaxf(tm, __shfl_xor(tm, 32));

            // unconditional exp with the CURRENT m_run
#pragma unroll
            for (int kc = 0; kc < 4; kc++)
#pragma unroll
                for (int i = 0; i < 4; i++) e[qg][kc][i] = EXP2(e[qg][kc][i] - m_run[qg]);

            // rare fix-up: a row's max grew by more than 8 (exp2 domain)
            if (!__all(tm <= m_run[qg] + 8.f)) {
                float nm = fmaxf(m_run[qg], tm);
                float sc = EXP2(m_run[qg] - nm);
                m_run[qg] = nm;
#pragma unroll
                for (int kc = 0; kc < 4; kc++)
#pragma unroll
                    for (int i = 0; i < 4; i++) e[qg][kc][i] *= sc;
#pragma unroll
                for (int i = 0; i < 4; i++) {
                    float sci = __shfl(sc, (lane & 48) | (g * 4 + i));
                    lsum[qg][i] *= sci;
#pragma unroll
                    for (int d = 0; d < 4; d++) o[qg][d][i] *= sci;
                }
            }

            // P -> per-wave LDS (swizzled b64 writes)
#pragma unroll
            for (int kc = 0; kc < 4; kc++) {
                h16x4 pk;
#pragma unroll
                for (int i = 0; i < 4; i++) pk[i] = (half_t)e[qg][kc][i];
                *(h16x4*)&Pl[wid][qg * 16 + r][SW(r, 2 * kc + (g >> 1)) + (g & 1) * 4] = pk;
            }
        }
    };

    auto PV = [&]() {
        asm volatile("s_waitcnt lgkmcnt(0)" ::: "memory");
        __builtin_amdgcn_sched_barrier(0);
        __builtin_amdgcn_s_setprio(1);
#pragma unroll
        for (int ks = 0; ks < 2; ks++) {
            h16x8 pf0 = *(const h16x8*)&Pl[wid][r][SW(r, ks * 4 + g)];
            h16x8 pf1 = *(const h16x8*)&Pl[wid][16 + r][SW(r, ks * 4 + g)];
#pragma unroll
            for (int d = 0; d < 4; d++) {
                o[0][d] = MFMA16(pf0, vf[d * 2 + ks], o[0][d]);
                o[1][d] = MFMA16(pf1, vf[d * 2 + ks], o[1][d]);
            }
            // denominator: lsum += P @ ones (full 32-k sum, o-layout)
            lsum[0] = MFMA16(pf0, ones, lsum[0]);
            lsum[1] = MFMA16(pf1, ones, lsum[1]);
        }
        __builtin_amdgcn_s_setprio(0);
    };

    // prologue: e for tile 0
    f32x4 eA[2][4], eB[2][4];
    loadK(0);
    QKT(eA);
    loadK(1);

    for (int kt = 0; kt < 32; kt += 2) {
        // ---- tile kt (state in eA) ----
        loadV(kt);                  // V latency covered by softmax
        SOFTMAX_P(eA);              // ends with P ds_writes
        QKT(eB);                    // tile kt+1 MFMAs drain the ds_write latency
        loadK((kt + 2) & 31);       // kf free after QKT; wraps (harmless)
        PV();                       // lgkmcnt(0) nearly free
        // ---- tile kt+1 (state in eB) ----
        loadV(kt + 1);
        SOFTMAX_P(eB);
        QKT(eA);                    // tile kt+2 (garbage on last pair, unused)
        loadK((kt + 3) & 31);
        PV();
    }

    // epilogue: lsum already holds per-row denominators in o-layout
#pragma unroll
    for (int qg = 0; qg < 2; qg++)
#pragma unroll
        for (int i = 0; i < 4; i++) {
            float inv = 1.0f / lsum[qg][i];
            int s = q0 + qg * 16 + g * 4 + i;
            float* op = out + (size_t)(b * 2048 + s) * 1024 + h * 64 + r;
#pragma unroll
            for (int d = 0; d < 4; d++) op[d * 16] = o[qg][d][i] * inv;
        }
}

// ---------------------------------------------------------------------------
extern "C" void kernel_launch(void* const* d_in, const int* in_sizes, int n_in,
                              void* d_out, int out_size, void* d_ws, size_t ws_size,
                              hipStream_t stream) {
    const float* x  = (const float*)d_in[0];
    const float* Wq = (const float*)d_in[1];
    const float* bq = (const float*)d_in[2];
    const float* Wk = (const float*)d_in[3];
    const float* bk = (const float*)d_in[4];
    const float* Wv = (const float*)d_in[5];
    const float* bv = (const float*)d_in[6];
    float* out = (float*)d_out;

    half_t* xh  = (half_t*)d_ws;
    half_t* Wt  = (half_t*)((char*)d_ws + (size_t)8 * 1024 * 1024);
    half_t* qkv = (half_t*)((char*)d_ws + (size_t)14 * 1024 * 1024);
    half_t* Qh  = qkv;
    half_t* Kh  = qkv + (size_t)4194304;   // Kswz
    half_t* Vth = qkv + (size_t)8388608;   // Vswz

    cvt_kernel<<<5120, 256, 0, stream>>>(x, Wq, Wk, Wv, xh, Wt);
    gemm_qkv_kernel<<<dim3(8, 32, 3), 256, 0, stream>>>(xh, Wt, bq, bk, bv, qkv);
    attn_kernel<<<dim3(512), 256, 0, stream>>>(Qh, Kh, Vth, out);
}